// Round 1
// baseline (281.457 us; speedup 1.0000x reference)
//
#include <hip/hip_runtime.h>
#include <cstdint>
#include <cstddef>

#define N_DIM 4096
#define M_DIM 4096
#define D_DIM 4096

typedef unsigned short u16;
typedef u16   u16x4 __attribute__((ext_vector_type(4)));
typedef u16   u16x8 __attribute__((ext_vector_type(8)));
typedef short s16x8 __attribute__((ext_vector_type(8)));   // 8 bf16 (4 VGPRs)
typedef float f32x4 __attribute__((ext_vector_type(4)));   // MFMA accumulator

// ---------- fp32 -> bf16 (RTNE) ----------
__device__ __forceinline__ u16 f2bf(float f) {
    union { float f; uint32_t u; } v; v.f = f;
    uint32_t u = v.u;
    uint32_t r = u + 0x7fffu + ((u >> 16) & 1u);
    return (u16)(r >> 16);
}

// 32 B loads / 16 B stores per lane per iteration.
__global__ __launch_bounds__(256) void convert_both(
    const float* __restrict__ A, const float* __restrict__ B,
    u16* __restrict__ Oa, u16* __restrict__ Ob) {
    const size_t nv8 = (size_t)N_DIM * D_DIM / 8;
    size_t gid = (size_t)blockIdx.x * blockDim.x + threadIdx.x;
    size_t stride = (size_t)gridDim.x * blockDim.x;
    for (size_t i = gid; i < nv8; i += stride) {
        float4 v0 = ((const float4*)A)[2 * i];
        float4 v1 = ((const float4*)A)[2 * i + 1];
        u16x8 o;
        o[0] = f2bf(v0.x); o[1] = f2bf(v0.y); o[2] = f2bf(v0.z); o[3] = f2bf(v0.w);
        o[4] = f2bf(v1.x); o[5] = f2bf(v1.y); o[6] = f2bf(v1.z); o[7] = f2bf(v1.w);
        ((u16x8*)Oa)[i] = o;
    }
    for (size_t i = gid; i < nv8; i += stride) {
        float4 v0 = ((const float4*)B)[2 * i];
        float4 v1 = ((const float4*)B)[2 * i + 1];
        u16x8 o;
        o[0] = f2bf(v0.x); o[1] = f2bf(v0.y); o[2] = f2bf(v0.z); o[3] = f2bf(v0.w);
        o[4] = f2bf(v1.x); o[5] = f2bf(v1.y); o[6] = f2bf(v1.z); o[7] = f2bf(v1.w);
        ((u16x8*)Ob)[i] = o;
    }
}

// ---------- async global->LDS, 16B/lane, wave-uniform LDS base ----------
__device__ __forceinline__ void g2l16(const u16* g, u16* l) {
    __builtin_amdgcn_global_load_lds(
        (const __attribute__((address_space(1))) void*)g,
        (__attribute__((address_space(3))) void*)l,
        16, 0, 0);
}

// ---- LDS geometry ----
// 8 independent 16 KB regions: {A,B} x {buf0,buf1} x {khalf0,khalf1}.
// Region = 256 rows x 32 bf16 (one K-half of a 256x64 tile).
// Row = 64 B = 4 chunks of 16 B. XOR swizzle: logical chunk c of row r lives
// at physical chunk c ^ ((r>>1)&3). Fragment reads (16 rows x 1 chunk per
// 16-lane group) then spread over (row parity, phys chunk) = 8 distinct
// 4-bank groups x 2 lanes -> 2-way access = free (m136). Inverse swizzle is
// applied on the GLOBAL source chunk at staging (global_load_lds LDS dest
// must stay wave-uniform-base + lane*16).

// stage one 256x32 region (1024 chunks): 2 global_load_lds per thread
__device__ __forceinline__ void stage_half(const u16* __restrict__ G,
                                           u16* region, int wave, int lane) {
    #pragma unroll
    for (int jj = 0; jj < 2; ++jj) {
        int grp = jj * 8 + wave;            // 0..15, wave-uniform
        int s   = grp * 64 + lane;          // LDS chunk slot 0..1023
        int r   = s >> 2;                   // row 0..255
        int c   = (s & 3) ^ ((r >> 1) & 3); // inverse swizzle -> global chunk
        g2l16(G + (size_t)r * D_DIM + c * 8, region + grp * 512);
    }
}

// LDS -> register MFMA fragment (8 bf16, ds_read_b128)
__device__ __forceinline__ s16x8 frag(const u16* region, int row, int cbq) {
    int c = cbq ^ ((row >> 1) & 3);
    return *(const s16x8*)&region[row * 32 + c * 8];
}

// One phase: ds-read A-frags (+B-frags on odd phases, reused on even),
// issue one region's prefetch, raw barrier, setprio-wrapped 16 MFMA,
// counted vmcnt(8) before the end barrier of even phases (never 0).
#define PHASE(AR, BR, MH, SG, SL, DOVM)                                       \
  {                                                                           \
    s16x8 af[4];                                                              \
    _Pragma("unroll")                                                         \
    for (int i = 0; i < 4; ++i)                                               \
      af[i] = frag((AR), waveM * 128 + ((MH) * 4 + i) * 16 + fr, cbq);        \
    if ((MH) == 0) {                                                          \
      _Pragma("unroll")                                                       \
      for (int j = 0; j < 4; ++j)                                             \
        bf[j] = frag((BR), waveN * 64 + j * 16 + fr, cbq);                    \
    }                                                                         \
    stage_half((SG), (SL), wave, lane);                                       \
    asm volatile("s_barrier" ::: "memory");                                   \
    __builtin_amdgcn_s_setprio(1);                                            \
    _Pragma("unroll")                                                         \
    for (int i = 0; i < 4; ++i) {                                             \
      _Pragma("unroll")                                                       \
      for (int j = 0; j < 4; ++j)                                             \
        acc[(MH) * 4 + i][j] = __builtin_amdgcn_mfma_f32_16x16x32_bf16(       \
            af[i], bf[j], acc[(MH) * 4 + i][j], 0, 0, 0);                     \
    }                                                                         \
    __builtin_amdgcn_s_setprio(0);                                            \
    if (DOVM) asm volatile("s_waitcnt vmcnt(8)" ::: "memory");                \
    asm volatile("s_barrier" ::: "memory");                                   \
  }

// 256x256 macro-tile, BK=64, 8-phase pipelined schedule, 512 threads.
// Per 2-K-tile iteration: 8 phases, each stages exactly one region; a
// region staged in phase p is first read 6 phases later. Steady-state
// in-flight: 8-12 loads/thread; vmcnt(8) at even-phase ends gates exactly
// the regions the next odd phase reads (per-wave wait BEFORE a barrier =>
// after the barrier all waves' shares have landed).
__global__ __launch_bounds__(512) void gemm_bt_bf16(
    const u16* __restrict__ A, const u16* __restrict__ B, float* __restrict__ C) {
    __shared__ __align__(16) u16 sm[65536];            // 128 KB
    u16* sA00 = sm;          u16* sA01 = sm + 8192;    // buf0 khalf0/1 (A)
    u16* sA10 = sm + 16384;  u16* sA11 = sm + 24576;   // buf1 khalf0/1 (A)
    u16* sB00 = sm + 32768;  u16* sB01 = sm + 40960;
    u16* sB10 = sm + 49152;  u16* sB11 = sm + 57344;

    const int tid   = threadIdx.x;
    const int lane  = tid & 63;
    const int wave  = tid >> 6;       // 0..7
    const int waveM = wave >> 2;      // 0..1
    const int waveN = wave & 3;       // 0..3
    const int fr    = lane & 15;      // frag row
    const int cbq   = lane >> 4;      // frag k-chunk within 32-K slice

    // XCD-compact swizzle: 256 blocks, 16x16 tile grid; each XCD (lin%8)
    // owns a 4x8 tile rectangle.
    const int lin  = blockIdx.x;
    const int xcd  = lin & 7;
    const int j    = lin >> 3;                    // 0..31
    const int tileY = (xcd >> 1) * 4 + (j & 3);   // 0..15
    const int tileX = (xcd & 1) * 8 + (j >> 2);   // 0..15
    const int rowBase = tileY * 256;
    const int colBase = tileX * 256;

    const u16* Abase = A + (size_t)rowBase * D_DIM;
    const u16* Bbase = B + (size_t)colBase * D_DIM;

    f32x4 acc[8][4] = {};
    s16x8 bf[4];

    // Prologue: issue 6 regions (tile0 kh0/kh1, tile1 kh0) = 12 loads/thread,
    // then wait oldest 4 (tile0 kh0) -> same in-flight set {b0kh1, b1kh0}
    // = 8 loads as the steady-state iteration entry.
    stage_half(Abase,      sA00, wave, lane);
    stage_half(Bbase,      sB00, wave, lane);
    stage_half(Abase + 32, sA01, wave, lane);
    stage_half(Bbase + 32, sB01, wave, lane);
    stage_half(Abase + 64, sA10, wave, lane);
    stage_half(Bbase + 64, sB10, wave, lane);
    asm volatile("s_waitcnt vmcnt(8)" ::: "memory");
    asm volatile("s_barrier" ::: "memory");

    #pragma unroll 1
    for (int t = 0; t < 64; t += 2) {
        const int t2 = (t + 2 < 64) ? t + 2 : 62;  // clamped tail re-stage
        const int t3 = (t + 3 < 64) ? t + 3 : 62;  // (written, never read)
        const u16* As1 = Abase + (t + 1) * 64;
        const u16* Bs1 = Bbase + (t + 1) * 64;
        const u16* As2 = Abase + t2 * 64;
        const u16* Bs2 = Bbase + t2 * 64;
        const u16* As3 = Abase + t3 * 64;
        const u16* Bs3 = Bbase + t3 * 64;

        // tile t (buf0): ks=0 (kh0) then ks=1 (kh1)
        PHASE(sA00, sB00, 0, As1 + 32, sA11, 0)   // stage b1kh1 <- t+1
        PHASE(sA00, sB00, 1, Bs1 + 32, sB11, 1)
        PHASE(sA01, sB01, 0, As2,      sA00, 0)   // stage b0kh0 <- t+2
        PHASE(sA01, sB01, 1, Bs2,      sB00, 1)
        // tile t+1 (buf1)
        PHASE(sA10, sB10, 0, As2 + 32, sA01, 0)   // stage b0kh1 <- t+2
        PHASE(sA10, sB10, 1, Bs2 + 32, sB01, 1)
        PHASE(sA11, sB11, 0, As3,      sA10, 0)   // stage b1kh0 <- t+3
        PHASE(sA11, sB11, 1, Bs3,      sB10, 1)
    }

    // Epilogue. C/D layout (verified m89/m91): col = lane&15, row = (lane>>4)*4 + reg
    #pragma unroll
    for (int mt = 0; mt < 8; ++mt) {
        int gr0 = rowBase + waveM * 128 + mt * 16 + (lane >> 4) * 4;
        #pragma unroll
        for (int nt = 0; nt < 4; ++nt) {
            int gc = colBase + waveN * 64 + nt * 16 + (lane & 15);
            #pragma unroll
            for (int r = 0; r < 4; ++r)
                C[(size_t)(gr0 + r) * M_DIM + gc] = acc[mt][nt][r];
        }
    }
}

extern "C" void kernel_launch(void* const* d_in, const int* in_sizes, int n_in,
                              void* d_out, int out_size, void* d_ws, size_t ws_size,
                              hipStream_t stream) {
    const float* A32 = (const float*)d_in[0];
    const float* B32 = (const float*)d_in[1];
    float* C = (float*)d_out;

    u16* Abf = (u16*)d_ws;
    u16* Bbf = Abf + (size_t)N_DIM * D_DIM;

    convert_both<<<4096, 256, 0, stream>>>(A32, B32, Abf, Bbf);
    gemm_bt_bf16<<<256, 512, 0, stream>>>(Abf, Bbf, C);
}